// Round 2
// baseline (368.055 us; speedup 1.0000x reference)
//
#include <hip/hip_runtime.h>
#include <hip/hip_bf16.h>
#include <math.h>

// Problem constants
#define NB 32768   // batch
#define NH 256     // hidden = nsync
#define NI 128     // input

typedef __attribute__((ext_vector_type(8))) short short8;  // 8 x bf16 (4 VGPR) mfma frag
typedef __attribute__((ext_vector_type(4))) float f32x4;   // mfma accum

__device__ __forceinline__ float b2f(unsigned int u) {
    union { float f; unsigned int i; } v; v.i = (u & 0xffffu) << 16; return v.f;
}
__device__ __forceinline__ unsigned short f2b(float f) {
    union { float f; unsigned int i; } v; v.f = f;
    unsigned int x = v.i;
    return (unsigned short)((x + 0x7fffu + ((x >> 16) & 1u)) >> 16);
}
__device__ __forceinline__ void unpack8(uint4 v, float* o) {
    o[0]=b2f(v.x); o[1]=b2f(v.x>>16);
    o[2]=b2f(v.y); o[3]=b2f(v.y>>16);
    o[4]=b2f(v.z); o[5]=b2f(v.z>>16);
    o[6]=b2f(v.w); o[7]=b2f(v.w>>16);
}
__device__ __forceinline__ uint4 pack8(const float* f) {
    uint4 r;
    r.x = (unsigned)f2b(f[0]) | ((unsigned)f2b(f[1])<<16);
    r.y = (unsigned)f2b(f[2]) | ((unsigned)f2b(f[3])<<16);
    r.z = (unsigned)f2b(f[4]) | ((unsigned)f2b(f[5])<<16);
    r.w = (unsigned)f2b(f[6]) | ((unsigned)f2b(f[7])<<16);
    return r;
}

// scalar per-step control, recomputed from the norm accumulators
struct StepCtl { bool run; bool upd; float factor; };
__device__ __forceinline__ StepCtl step_ctl(const float* norms, int t) {
    bool done = false, done_prev = false, brk_prev = false;
    for (int s = 0; s < t; ++s) {
        bool brk = false;
        if (!done) {
            float nm = norms[s] * (1.0f / 8388608.0f);
            brk = (s >= 3) && (nm < 0.01f);
        }
        if (s == t - 1) { done_prev = done; brk_prev = brk; }
        done = done || brk;
    }
    StepCtl c;
    c.upd = (t > 0) && !done_prev;
    c.factor = brk_prev ? 1.0f : 2.0f;
    c.run = !done;
    return c;
}

// ---------------------------------------------------------------------------
// k_init: h0 (f32) -> h_ws bf16; W concat [Wfx|Wfh|Wm] -> bf16 slices (linear);
//         rs = sigmoid(r_param); zero norms. Runs every launch (replay-safe).
// blocks 0..8191: h convert; 8192..8271: W; 8272: rs + norms
// ---------------------------------------------------------------------------
__global__ __launch_bounds__(256) void k_init(const float* __restrict__ h0,
                                              const float* __restrict__ Wf,
                                              const float* __restrict__ Wm,
                                              const float* __restrict__ r_param,
                                              unsigned short* __restrict__ h_ws,
                                              unsigned short* __restrict__ wsW,
                                              float* __restrict__ rs,
                                              float* __restrict__ norms) {
    int b = blockIdx.x, tid = threadIdx.x;
    if (b < 8192) {
        int idx4 = (b * 256 + tid) * 4;
        float4 hv = *(const float4*)(h0 + idx4);
        uint2 pk;
        pk.x = (unsigned)f2b(hv.x) | ((unsigned)f2b(hv.y) << 16);
        pk.y = (unsigned)f2b(hv.z) | ((unsigned)f2b(hv.w) << 16);
        *(uint2*)(h_ws + idx4) = pk;
    } else if (b < 8272) {
        int gt = (b - 8192) * 256 + tid;       // 0..20479
        int s = gt >> 10;                      // slice 0..19 (K chunks of 32)
        int rem = gt & 1023;
        int n = rem >> 2, q = rem & 3;         // n: output col, q: 8-elem group
        float vals[8];
        #pragma unroll
        for (int j = 0; j < 8; ++j) {
            int kg = s * 32 + q * 8 + j;       // global K index 0..639
            vals[j] = (kg < 384) ? Wf[n * 384 + kg] : Wm[n * 256 + (kg - 384)];
        }
        *(uint4*)(wsW + (size_t)s * 8192 + (n * 4 + q) * 8) = pack8(vals);
    } else {
        if (tid < 256) rs[tid] = 1.0f / (1.0f + expf(-r_param[tid]));
        if (tid < 8)   norms[tid] = 0.0f;
    }
}

// ---------------------------------------------------------------------------
// k_basex: base_x = x @ Wfx^T + bf  (bf16 out).  BM=64, 4 waves, K=128.
// ---------------------------------------------------------------------------
__global__ __launch_bounds__(256, 2) void k_basex(const float* __restrict__ x,
                                                  const float* __restrict__ bfv,
                                                  const unsigned short* __restrict__ wsW,
                                                  unsigned short* __restrict__ basex) {
    __shared__ unsigned short xA[64 * 128];    // 16KB, swizzled
    __shared__ unsigned short sW[2 * 8192];    // 32KB dbuf
    int tid = threadIdx.x, r0 = blockIdx.x * 64;

    // stage x -> bf16 LDS (swizzle byte ^= (row&7)<<4)
    #pragma unroll
    for (int i = 0; i < 8; ++i) {
        int g = i * 256 + tid;                 // 2048 float4 quads
        int row = g >> 5, c4 = (g & 31) * 4;
        float4 xv = *(const float4*)(x + (r0 + row) * 128 + c4);
        unsigned int byte = (unsigned)(row * 256 + c4 * 2) ^ (unsigned)((row & 7) << 4);
        uint2 pk;
        pk.x = (unsigned)f2b(xv.x) | ((unsigned)f2b(xv.y) << 16);
        pk.y = (unsigned)f2b(xv.z) | ((unsigned)f2b(xv.w) << 16);
        *(uint2*)((char*)xA + byte) = pk;
    }

    int wave = tid >> 6, lane = tid & 63, lrow = lane & 15, lq = lane >> 4;
    f32x4 acc[4][4];
    #pragma unroll
    for (int m = 0; m < 4; ++m)
        #pragma unroll
        for (int n = 0; n < 4; ++n) { f32x4 z = {0.f,0.f,0.f,0.f}; acc[m][n] = z; }

    // prologue: stage W slice 0 into buf0 (swizzled)
    #pragma unroll
    for (int j = 0; j < 4; ++j) {
        int gr = wave * 256 + j * 64 + lane;
        uint4 w = *(const uint4*)(wsW + 0 * 8192 + gr * 8);
        int n = gr >> 2, q = gr & 3;
        unsigned int byte = (unsigned)(n * 64 + q * 16) ^ (unsigned)((n & 7) << 4);
        *(uint4*)((char*)sW + byte) = w;
    }
    __syncthreads();

    for (int kk = 0; kk < 4; ++kk) {
        int cur = kk & 1;
        uint4 wreg[4];
        if (kk < 3) {
            #pragma unroll
            for (int j = 0; j < 4; ++j) {
                int gr = wave * 256 + j * 64 + lane;
                wreg[j] = *(const uint4*)(wsW + (kk + 1) * 8192 + gr * 8);
            }
        }
        short8 a[4];
        int k = kk * 32 + lq * 8;
        #pragma unroll
        for (int m = 0; m < 4; ++m) {
            int row = m * 16 + lrow;
            unsigned int byte = (unsigned)(row * 256 + k * 2) ^ (unsigned)((row & 7) << 4);
            a[m] = *(const short8*)((const char*)xA + byte);
        }
        short8 bfrag[4];
        #pragma unroll
        for (int n = 0; n < 4; ++n) {
            int nr = wave * 64 + n * 16 + lrow;
            unsigned int byte = (unsigned)(nr * 64 + lq * 16) ^ (unsigned)((nr & 7) << 4);
            bfrag[n] = *(const short8*)((const char*)sW + (cur * 16384 + byte));
        }
        #pragma unroll
        for (int m = 0; m < 4; ++m)
            #pragma unroll
            for (int n = 0; n < 4; ++n)
                acc[m][n] = __builtin_amdgcn_mfma_f32_16x16x32_bf16(a[m], bfrag[n], acc[m][n], 0, 0, 0);
        if (kk < 3) {
            int nxt = cur ^ 1;
            #pragma unroll
            for (int j = 0; j < 4; ++j) {
                int gr = wave * 256 + j * 64 + lane;
                int n = gr >> 2, q = gr & 3;
                unsigned int byte = (unsigned)(n * 64 + q * 16) ^ (unsigned)((n & 7) << 4);
                *(uint4*)((char*)sW + (nxt * 16384 + byte)) = wreg[j];
            }
        }
        __syncthreads();
    }

    // epilogue: + bias, store bf16
    #pragma unroll
    for (int m = 0; m < 4; ++m)
        #pragma unroll
        for (int n = 0; n < 4; ++n)
            #pragma unroll
            for (int r = 0; r < 4; ++r) {
                int row = m * 16 + lq * 4 + r;          // C/D: col=lane&15, row=(lane>>4)*4+reg
                int col = wave * 64 + n * 16 + lrow;
                float v = acc[m][n][r] + bfv[col];
                basex[(r0 + row) * 256 + col] = f2b(v);
            }
}

// ---------------------------------------------------------------------------
// k_step: one recurrent step. BM=64 rows/block, 512 blocks, 256 threads.
// ---------------------------------------------------------------------------
__global__ __launch_bounds__(256, 2) void k_step(int t,
                                                 unsigned short* __restrict__ h_ws,
                                                 const float* __restrict__ alpha_in,
                                                 float* __restrict__ alpha_out,
                                                 const unsigned short* __restrict__ basex,
                                                 unsigned short* __restrict__ hu,
                                                 const unsigned short* __restrict__ wsW,
                                                 const float* __restrict__ rs,
                                                 float* __restrict__ norms,
                                                 const float* __restrict__ beta0,
                                                 const int* __restrict__ idxl,
                                                 const int* __restrict__ idxr,
                                                 const float* __restrict__ A_param,
                                                 const float* __restrict__ tau_param) {
    __shared__ unsigned short sA[64 * 256];    // 32KB sync tile (swizzled)
    __shared__ unsigned short sW[2 * 8192];    // 32KB W dbuf
    const int tid = threadIdx.x;
    const int r0 = blockIdx.x * 64;

    StepCtl ctl = step_ctl(norms, t);
    if (!ctl.run && !ctl.upd) return;

    // ---- phase A: apply previous step's h update (bf16 state, in place)
    if (ctl.upd) {
        #pragma unroll
        for (int i = 0; i < 8; ++i) {
            int g = i * 256 + tid;             // 2048 16B granules in 64x256 tile
            int row = g >> 5;
            int c8 = (g & 31) * 8;
            int off = (r0 + row) * 256 + c8;
            uint4 hv = *(const uint4*)(h_ws + off);
            uint4 uv = *(const uint4*)(hu + off);
            float hf[8], uf[8], nf[8];
            unpack8(hv, hf); unpack8(uv, uf);
            #pragma unroll
            for (int j = 0; j < 8; ++j) nf[j] = hf[j] + ctl.factor * uf[j];
            *(uint4*)(h_ws + off) = pack8(nf);
        }
    }
    if (!ctl.run) return;
    __syncthreads();   // h_ws writes visible block-wide

    // ---- phase B: alpha/beta/sync elementwise; sync -> LDS (bf16, swizzled)
    for (int i = 0; i < 16; ++i) {
        int g = i * 256 + tid;                 // 4096 float quads
        int row = g >> 6;
        int c4 = (g & 63) * 4;
        int roff = (r0 + row) * 256;
        float4 av  = *(const float4*)(alpha_in + roff + c4);
        float4 b0v = *(const float4*)(beta0 + roff + c4);
        float4 rv  = *(const float4*)(rs + c4);
        float rsa[4] = {rv.x, rv.y, rv.z, rv.w};
        float aa[4]  = {av.x, av.y, av.z, av.w};
        float bb[4]  = {b0v.x, b0v.y, b0v.z, b0v.w};
        float an[4], sy[4];
        #pragma unroll
        for (int j = 0; j < 4; ++j) {
            int c = c4 + j;
            float hl = b2f(h_ws[roff + idxl[c]]);
            float hr = b2f(h_ws[roff + idxr[c]]);
            float a_new = rsa[j] * aa[j] + hl * hr;
            float p = 1.0f, ss = 0.0f;
            for (int u = 0; u <= t; ++u) { ss += p; p *= rsa[j]; }   // beta_{t+1} closed form
            float b_new = p * bb[j] + ss;
            sy[j] = a_new / (sqrtf(b_new) + 1e-6f);
            an[j] = a_new;
        }
        *(float4*)(alpha_out + roff + c4) = make_float4(an[0], an[1], an[2], an[3]);
        unsigned int byte = (unsigned)(row * 512 + c4 * 2) ^ (unsigned)((row & 7) << 4);
        uint2 pk;
        pk.x = (unsigned)f2b(sy[0]) | ((unsigned)f2b(sy[1]) << 16);
        pk.y = (unsigned)f2b(sy[2]) | ((unsigned)f2b(sy[3]) << 16);
        *(uint2*)((char*)sA + byte) = pk;
    }

    // ---- phase C: GEMM  [h | sync] (64x512) @ [Wfh|Wm]^T -> 64x256
    const unsigned short* wsrc = wsW + 4 * 8192;   // step slices 4..19
    const int wave = tid >> 6, lane = tid & 63, lrow = lane & 15, lq = lane >> 4;
    f32x4 acc[4][4];
    #pragma unroll
    for (int m = 0; m < 4; ++m)
        #pragma unroll
        for (int n = 0; n < 4; ++n) { f32x4 z = {0.f,0.f,0.f,0.f}; acc[m][n] = z; }

    // prologue: stage W slice 0
    #pragma unroll
    for (int j = 0; j < 4; ++j) {
        int gr = wave * 256 + j * 64 + lane;
        uint4 w = *(const uint4*)(wsrc + gr * 8);
        int n = gr >> 2, q = gr & 3;
        unsigned int byte = (unsigned)(n * 64 + q * 16) ^ (unsigned)((n & 7) << 4);
        *(uint4*)((char*)sW + byte) = w;
    }
    __syncthreads();   // sA + buf0 ready

    for (int kk = 0; kk < 16; ++kk) {
        int cur = kk & 1;
        uint4 wreg[4];
        if (kk < 15) {
            #pragma unroll
            for (int j = 0; j < 4; ++j) {
                int gr = wave * 256 + j * 64 + lane;
                wreg[j] = *(const uint4*)(wsrc + (kk + 1) * 8192 + gr * 8);
            }
        }
        short8 a[4];
        if (kk < 8) {
            int k = kk * 32 + lq * 8;
            #pragma unroll
            for (int m = 0; m < 4; ++m) {
                int grow = r0 + m * 16 + lrow;
                a[m] = *(const short8*)(h_ws + grow * 256 + k);   // global bf16 h
            }
        } else {
            int ks = (kk - 8) * 32 + lq * 8;
            #pragma unroll
            for (int m = 0; m < 4; ++m) {
                int row = m * 16 + lrow;
                unsigned int byte = (unsigned)(row * 512 + ks * 2) ^ (unsigned)((row & 7) << 4);
                a[m] = *(const short8*)((const char*)sA + byte);
            }
        }
        short8 bfrag[4];
        #pragma unroll
        for (int n = 0; n < 4; ++n) {
            int nr = wave * 64 + n * 16 + lrow;
            unsigned int byte = (unsigned)(nr * 64 + lq * 16) ^ (unsigned)((nr & 7) << 4);
            bfrag[n] = *(const short8*)((const char*)sW + (cur * 16384 + byte));
        }
        #pragma unroll
        for (int m = 0; m < 4; ++m)
            #pragma unroll
            for (int n = 0; n < 4; ++n)
                acc[m][n] = __builtin_amdgcn_mfma_f32_16x16x32_bf16(a[m], bfrag[n], acc[m][n], 0, 0, 0);
        if (kk < 15) {
            int nxt = cur ^ 1;
            #pragma unroll
            for (int j = 0; j < 4; ++j) {
                int gr = wave * 256 + j * 64 + lane;
                int n = gr >> 2, q = gr & 3;
                unsigned int byte = (unsigned)(n * 64 + q * 16) ^ (unsigned)((n & 7) << 4);
                *(uint4*)((char*)sW + (nxt * 16384 + byte)) = wreg[j];
            }
        }
        __syncthreads();
    }

    // ---- phase D: epilogue  f = sin(base+drive)^2, hu, norm partial
    float tauv = tau_param[0];
    float inv_tau = 1.0f / log1pf(expf(tauv));
    float tsum = 0.0f;
    #pragma unroll
    for (int m = 0; m < 4; ++m)
        #pragma unroll
        for (int n = 0; n < 4; ++n)
            #pragma unroll
            for (int r = 0; r < 4; ++r) {
                int row = m * 16 + lq * 4 + r;
                int col = wave * 64 + n * 16 + lrow;
                int off = (r0 + row) * 256 + col;
                float arg = acc[m][n][r] + b2f(basex[off]);
                float s = __sinf(arg);
                float f = s * s;
                float hv = b2f(h_ws[off]);
                float dh = -hv * (inv_tau + f) + A_param[col] * f;
                float huv = 0.1f * dh;
                hu[off] = f2b(huv);
                tsum += fabsf(huv);
            }
    #pragma unroll
    for (int d = 32; d >= 1; d >>= 1) tsum += __shfl_down(tsum, d);
    __syncthreads();                       // safe to reuse sA as scratch
    float* red = (float*)sA;
    if (lane == 0) red[wave] = tsum;
    __syncthreads();
    if (tid == 0) atomicAdd(&norms[t], red[0] + red[1] + red[2] + red[3]);
}

// ---------------------------------------------------------------------------
// k_final: last h update; outputs are FLOAT32 (reference output dtype):
//   out[0 .. 8388607]            h_final
//   out[8388608 .. 16777215]     alpha_final
//   out[16777216 .. 25165823]    beta_final (closed form)
//   out[25165824]                last (as float)
// ---------------------------------------------------------------------------
__global__ __launch_bounds__(256) void k_final(const unsigned short* __restrict__ h_ws,
                                               const unsigned short* __restrict__ hu,
                                               const float* __restrict__ alpha_ws,
                                               const float* __restrict__ beta0,
                                               const float* __restrict__ rs,
                                               const float* __restrict__ norms,
                                               float* __restrict__ out) {
    bool done = false, exec5 = false;
    int last = 0;
    float f5 = 2.0f;
    for (int s = 0; s < 6; ++s) {
        if (!done) {
            last = s;
            float nm = norms[s] * (1.0f / 8388608.0f);
            bool brk = (s >= 3) && (nm < 0.01f);
            if (s == 5) { exec5 = true; f5 = brk ? 1.0f : 2.0f; }
            done = done || brk;
        }
    }
    int n_exec = last + 1;

    int tid = threadIdx.x;
    int idx4 = (blockIdx.x * 256 + tid) * 4;

    // h (f32 out)
    uint2 hv = *(const uint2*)(h_ws + idx4);
    uint2 uv = *(const uint2*)(hu + idx4);
    float hf[4] = {b2f(hv.x), b2f(hv.x >> 16), b2f(hv.y), b2f(hv.y >> 16)};
    float uf[4] = {b2f(uv.x), b2f(uv.x >> 16), b2f(uv.y), b2f(uv.y >> 16)};
    float4 ho;
    ho.x = exec5 ? (hf[0] + f5 * uf[0]) : hf[0];
    ho.y = exec5 ? (hf[1] + f5 * uf[1]) : hf[1];
    ho.z = exec5 ? (hf[2] + f5 * uf[2]) : hf[2];
    ho.w = exec5 ? (hf[3] + f5 * uf[3]) : hf[3];
    *(float4*)(out + idx4) = ho;

    // alpha (f32 out)
    float4 av = *(const float4*)(alpha_ws + idx4);
    *(float4*)(out + 8388608 + idx4) = av;

    // beta closed form with n_exec applications (f32 out)
    int c0 = idx4 & 255;
    float4 b0v = *(const float4*)(beta0 + idx4);
    float4 rv  = *(const float4*)(rs + c0);
    float bb[4] = {b0v.x, b0v.y, b0v.z, b0v.w};
    float rr[4] = {rv.x, rv.y, rv.z, rv.w};
    float4 bo;
    float* bop = (float*)&bo;
    #pragma unroll
    for (int j = 0; j < 4; ++j) {
        float p = 1.0f, ss = 0.0f;
        for (int u = 0; u < n_exec; ++u) { ss += p; p *= rr[j]; }
        bop[j] = p * bb[j] + ss;
    }
    *(float4*)(out + 16777216 + idx4) = bo;

    if (blockIdx.x == 0 && tid == 0) out[25165824] = (float)last;
}

// ---------------------------------------------------------------------------
extern "C" void kernel_launch(void* const* d_in, const int* in_sizes, int n_in,
                              void* d_out, int out_size, void* d_ws, size_t ws_size,
                              hipStream_t stream) {
    const float* x      = (const float*)d_in[0];
    const float* h0     = (const float*)d_in[1];
    const float* alpha0 = (const float*)d_in[2];
    const float* beta0  = (const float*)d_in[3];
    const float* Wf     = (const float*)d_in[4];
    const float* bfv    = (const float*)d_in[5];
    const float* tau    = (const float*)d_in[6];
    const float* rparam = (const float*)d_in[7];
    const float* Aparam = (const float*)d_in[8];
    const float* Wm     = (const float*)d_in[9];
    const int* idxl     = (const int*)d_in[10];
    const int* idxr     = (const int*)d_in[11];

    char* ws = (char*)d_ws;
    unsigned short* h_ws  = (unsigned short*)(ws + 0);           // bf16 [B][256]  16.78MB
    float*          alpha = (float*)(ws + 16777216);             // f32  [B][256]  33.55MB
    unsigned short* basex = (unsigned short*)(ws + 50331648);    // bf16 [B][256]  16.78MB
    unsigned short* hu    = (unsigned short*)(ws + 67108864);    // bf16 [B][256]  16.78MB
    unsigned short* wsW   = (unsigned short*)(ws + 83886080);    // bf16 20x8192   320KB
    float*          rs    = (float*)(ws + 84213760);             // f32 [256]
    float*          norms = (float*)(ws + 84214784);             // f32 [8]

    k_init<<<8273, 256, 0, stream>>>(h0, Wf, Wm, rparam, h_ws, wsW, rs, norms);
    k_basex<<<512, 256, 0, stream>>>(x, bfv, wsW, basex);
    for (int t = 0; t < 6; ++t) {
        const float* a_in = (t == 0) ? alpha0 : alpha;
        k_step<<<512, 256, 0, stream>>>(t, h_ws, a_in, alpha, basex, hu, wsW, rs, norms,
                                        beta0, idxl, idxr, Aparam, tau);
    }
    k_final<<<8192, 256, 0, stream>>>(h_ws, hu, alpha, beta0, rs, norms,
                                      (float*)d_out);
}